// Round 1
// baseline (17908.498 us; speedup 1.0000x reference)
//
#include <hip/hip_runtime.h>

typedef int v4i  __attribute__((ext_vector_type(4)));
typedef int v16i __attribute__((ext_vector_type(16)));

// ---- problem constants ----
#define N_IMG   32
#define C_IN    256
#define C_OUT   256
#define HWDIM   56
#define HW2     3136            // 56*56
#define SP_TOT  100352          // 32*56*56
#define OUT_TOT 25690112        // 32*256*56*56
#define OUT_NSTR 802816         // 256*3136

// x8p padded NHWC int8: [32][58][58][256]
#define XP_HSTR 14848           // 58*256
#define XP_NSTR 861184          // 58*58*256
#define XP_BYTES 27557888ull    // 32*861184
// packed weights: [cb2:8][tap:9][kb:8][lane:64][16B]
#define WP_CB2STR 73728         // 9*8*1024
#define WP_BYTES  589824ull

#define HAVE_I8MFMA __has_builtin(__builtin_amdgcn_mfma_i32_32x32x32_i8)

// ---------- pre-pass A: x NCHW int32 -> NHWC int8 with zero halo ----------
__global__ void dc_x_to_nhwc(const int* __restrict__ x, unsigned int* __restrict__ x8) {
    __shared__ unsigned int lds[64 * 65];   // [w:64][cig:64] +1-dword pad per row
    const int t = threadIdx.x;
    const int w = t & 63, q = t >> 6;
    const int n = blockIdx.x / HWDIM, h = blockIdx.x % HWDIM;

    if (w < HWDIM) {
        const int* xb = x + n * OUT_NSTR + h * HWDIM + w;   // walk ci via *3136
        #pragma unroll
        for (int it = 0; it < 16; ++it) {
            const int cg4 = q * 16 + it;      // dword group: ci = cg4*4 .. +3
            const int ci0 = cg4 * 4;
            unsigned v  =  ((unsigned)xb[(ci0 + 0) * HW2] & 0xff);
            v |= ((unsigned)xb[(ci0 + 1) * HW2] & 0xff) << 8;
            v |= ((unsigned)xb[(ci0 + 2) * HW2] & 0xff) << 16;
            v |= ((unsigned)xb[(ci0 + 3) * HW2] & 0xff) << 24;
            lds[w * 65 + cg4] = v;
        }
    }
    __syncthreads();
    // write x8p[n][h+1][w+1][ci] as dwords
    unsigned int* ob = x8 + (n * (XP_NSTR / 4) + (h + 1) * (XP_HSTR / 4) + 64); // +64 = (w=0 +1)*256B
    #pragma unroll
    for (int it = 0; it < 14; ++it) {       // 56*64 dwords = 3584 = 14*256
        const int f = it * 256 + t;
        const int w2 = f >> 6, cg = f & 63;
        if (w2 < HWDIM) ob[w2 * 64 + cg] = lds[w2 * 65 + cg];
    }
}

// ---------- pre-pass B: pack weights into per-lane fragment order ----------
// Wp[(((cb2*9 + t)*8 + kb)*64 + lane)*16 + j] = W[co=cb2*32+(lane&31)][ci=kb*32+(lane>>5)*16+j][kh][kw]
__global__ void dc_pack_w(const int* __restrict__ wt, unsigned int* __restrict__ wp) {
    const int tid = blockIdx.x * 256 + threadIdx.x;  // < 147456
    const int jq = tid & 3;
    const int l  = (tid >> 2) & 63;
    const int kb = (tid >> 8) & 7;
    const int r  = tid >> 11;          // 0..71
    const int t  = r % 9;
    const int cb2 = r / 9;             // 0..7
    const int co  = cb2 * 32 + (l & 31);
    const int ci0 = kb * 32 + (l >> 5) * 16 + jq * 4;
    const int kh = t / 3, kw = t - kh * 3;
    unsigned v = 0;
    #pragma unroll
    for (int k = 0; k < 4; ++k) {
        unsigned b = (unsigned)wt[((co * C_IN + ci0 + k) * 3 + kh) * 3 + kw];
        v |= (b & 0xff) << (8 * k);
    }
    wp[tid] = v;
}

// ---------- main kernel: implicit GEMM, no LDS ----------
#if HAVE_I8MFMA
__global__ __launch_bounds__(256, 2) void dc_mfma(const char* __restrict__ x8,
                                                  const char* __restrict__ wp,
                                                  int* __restrict__ out) {
    const int tid = threadIdx.x;
    const int l = tid & 63, wid = tid >> 6;
    const int lane31 = l & 31, hi = l >> 5;
    const int bid = blockIdx.x;
    const int cohalf = bid & 1, sb = bid >> 1;      // adjacent blocks share the s-tile (L2 reuse of X)
    const int cg = wid & 1, sg = wid >> 1;
    const int cobase = cohalf * 128 + cg * 64;
    const int sbase  = sb * 256 + sg * 128;

    // per n-fragment (spatial) setup
    const char* xp[4];
    int outb[4];
    #pragma unroll
    for (int ni = 0; ni < 4; ++ni) {
        const int s = sbase + ni * 32 + lane31;
        const int n = s / HW2;
        const int hw = s - n * HW2;
        const int h = hw / HWDIM;
        const int w = hw - h * HWDIM;
        xp[ni] = x8 + n * XP_NSTR + (h + 1) * XP_HSTR + (w + 1) * 256 + hi * 16;
        outb[ni] = n * OUT_NSTR + hw;
    }

    const int cb2_0 = cohalf * 4 + cg * 2;
    const char* wbase0 = wp + cb2_0 * WP_CB2STR + l * 16;

    v16i acc[2][4] = {};

    for (int t = 0; t < 9; ++t) {
        const int dh = t / 3 - 1, dw = t - (t / 3) * 3 - 1;
        const int xoff = (dh * 58 + dw) * 256;
        const char* xt0 = xp[0] + xoff;
        const char* xt1 = xp[1] + xoff;
        const char* xt2 = xp[2] + xoff;
        const char* xt3 = xp[3] + xoff;
        const char* wt0 = wbase0 + t * 8192;
        const char* wt1 = wt0 + WP_CB2STR;

        #pragma unroll
        for (int kb = 0; kb < 8; ++kb) {
            const v4i a0 = *(const v4i*)(wt0 + kb * 1024);
            const v4i a1 = *(const v4i*)(wt1 + kb * 1024);
            const v4i b0 = *(const v4i*)(xt0 + kb * 32);
            const v4i b1 = *(const v4i*)(xt1 + kb * 32);
            const v4i b2 = *(const v4i*)(xt2 + kb * 32);
            const v4i b3 = *(const v4i*)(xt3 + kb * 32);
            acc[0][0] = __builtin_amdgcn_mfma_i32_32x32x32_i8(a0, b0, acc[0][0], 0, 0, 0);
            acc[0][1] = __builtin_amdgcn_mfma_i32_32x32x32_i8(a0, b1, acc[0][1], 0, 0, 0);
            acc[0][2] = __builtin_amdgcn_mfma_i32_32x32x32_i8(a0, b2, acc[0][2], 0, 0, 0);
            acc[0][3] = __builtin_amdgcn_mfma_i32_32x32x32_i8(a0, b3, acc[0][3], 0, 0, 0);
            acc[1][0] = __builtin_amdgcn_mfma_i32_32x32x32_i8(a1, b0, acc[1][0], 0, 0, 0);
            acc[1][1] = __builtin_amdgcn_mfma_i32_32x32x32_i8(a1, b1, acc[1][1], 0, 0, 0);
            acc[1][2] = __builtin_amdgcn_mfma_i32_32x32x32_i8(a1, b2, acc[1][2], 0, 0, 0);
            acc[1][3] = __builtin_amdgcn_mfma_i32_32x32x32_i8(a1, b3, acc[1][3], 0, 0, 0);
        }
    }

    // C/D: col = lane&31 (spatial, contiguous), row = (r&3)+8*(r>>2)+4*hi (co)
    #pragma unroll
    for (int mi = 0; mi < 2; ++mi) {
        #pragma unroll
        for (int ni = 0; ni < 4; ++ni) {
            const v16i c = acc[mi][ni];
            int* ob = out + outb[ni] + (cobase + mi * 32 + 4 * hi) * HW2;
            #pragma unroll
            for (int r = 0; r < 16; ++r) {
                ob[((r & 3) + 8 * (r >> 2)) * HW2] = c[r];
            }
        }
    }
}
#endif

// ---------- fallback: direct conv (correct, slow) ----------
__global__ void dc_naive(const int* __restrict__ x, const int* __restrict__ wt,
                         int* __restrict__ out) {
    const int idx = blockIdx.x * 256 + threadIdx.x;
    if (idx >= OUT_TOT) return;
    const int w = idx % HWDIM;
    const int h = (idx / HWDIM) % HWDIM;
    const int co = (idx / HW2) & 255;
    const int n = idx / OUT_NSTR;
    const int* xn = x + n * OUT_NSTR;
    const int* wo = wt + co * (C_IN * 9);
    int acc = 0;
    for (int ci = 0; ci < C_IN; ++ci) {
        const int* xc = xn + ci * HW2;
        const int* wc = wo + ci * 9;
        #pragma unroll
        for (int kh = 0; kh < 3; ++kh) {
            const int hh = h + kh - 1;
            if ((unsigned)hh >= HWDIM) continue;
            #pragma unroll
            for (int kw = 0; kw < 3; ++kw) {
                const int ww = w + kw - 1;
                if ((unsigned)ww >= HWDIM) continue;
                acc += xc[hh * HWDIM + ww] * wc[kh * 3 + kw];
            }
        }
    }
    out[idx] = acc;
}

extern "C" void kernel_launch(void* const* d_in, const int* in_sizes, int n_in,
                              void* d_out, int out_size, void* d_ws, size_t ws_size,
                              hipStream_t stream) {
    const int* x  = (const int*)d_in[0];
    const int* wt = (const int*)d_in[1];
    int* out = (int*)d_out;

    const size_t need = XP_BYTES + WP_BYTES;
#if HAVE_I8MFMA
    if (ws_size >= need) {
        char* x8 = (char*)d_ws;
        unsigned int* wp = (unsigned int*)((char*)d_ws + XP_BYTES);
        hipMemsetAsync(d_ws, 0, XP_BYTES, stream);                     // zero halo
        hipLaunchKernelGGL(dc_x_to_nhwc, dim3(N_IMG * HWDIM), dim3(256), 0, stream,
                           x, (unsigned int*)x8);
        hipLaunchKernelGGL(dc_pack_w, dim3(576), dim3(256), 0, stream, wt, wp);
        hipLaunchKernelGGL(dc_mfma, dim3(784), dim3(256), 0, stream,
                           (const char*)x8, (const char*)wp, out);
        return;
    }
#endif
    hipLaunchKernelGGL(dc_naive, dim3((OUT_TOT + 255) / 256), dim3(256), 0, stream,
                       x, wt, out);
}

// Round 2
// 200.971 us; speedup vs baseline: 89.1097x; 89.1097x over previous
//
#include <hip/hip_runtime.h>

typedef int v4i  __attribute__((ext_vector_type(4)));
typedef int v16i __attribute__((ext_vector_type(16)));

// ---- problem constants ----
#define N_IMG   32
#define C_IN    256
#define C_OUT   256
#define HWDIM   56
#define HW2     3136            // 56*56
#define OUT_TOT 25690112        // 32*256*56*56
#define OUT_NSTR 802816         // 256*3136

// x8p padded NHWC int8 per image: [58][58][256] bytes
#define XP_HSTR 14848           // 58*256
#define XP_NSTR 861184          // 58*58*256 bytes per image
// packed weights: [cb2:8][tap:9][kb:8][lane:64][16B]
#define WP_CB2STR 73728         // 9*8*1024
#define WP_BYTES  589824ull

// ---------- pre-pass A: x NCHW int32 -> NHWC int8 with zero halo ----------
// one block per (image, h-row); x8 covers `chunk` images starting at n0
__global__ void dc_x_to_nhwc(const int* __restrict__ x, unsigned int* __restrict__ x8,
                             int n0) {
    __shared__ unsigned int lds[64 * 65];   // [w:64][cig:64] +1-dword pad per row
    const int t = threadIdx.x;
    const int w = t & 63, q = t >> 6;
    const int nl = blockIdx.x / HWDIM, h = blockIdx.x % HWDIM;

    if (w < HWDIM) {
        const int* xb = x + (size_t)(n0 + nl) * OUT_NSTR + h * HWDIM + w;
        #pragma unroll
        for (int it = 0; it < 16; ++it) {
            const int cg4 = q * 16 + it;      // dword group: ci = cg4*4 .. +3
            const int ci0 = cg4 * 4;
            unsigned v  =  ((unsigned)xb[(ci0 + 0) * HW2] & 0xff);
            v |= ((unsigned)xb[(ci0 + 1) * HW2] & 0xff) << 8;
            v |= ((unsigned)xb[(ci0 + 2) * HW2] & 0xff) << 16;
            v |= ((unsigned)xb[(ci0 + 3) * HW2] & 0xff) << 24;
            lds[w * 65 + cg4] = v;
        }
    }
    __syncthreads();
    // write x8p[nl][h+1][w+1][ci] as dwords
    unsigned int* ob = x8 + (nl * (XP_NSTR / 4) + (h + 1) * (XP_HSTR / 4) + 64);
    #pragma unroll
    for (int it = 0; it < 14; ++it) {       // 56*64 dwords = 3584 = 14*256
        const int f = it * 256 + t;
        const int w2 = f >> 6, cg = f & 63;
        if (w2 < HWDIM) ob[w2 * 64 + cg] = lds[w2 * 65 + cg];
    }
}

// ---------- pre-pass B: pack weights into per-lane fragment order ----------
// Wp[(((cb2*9 + t)*8 + kb)*64 + lane)*16 + j] =
//   W[co=cb2*32+(lane&31)][ci=kb*32+(lane>>5)*16+j][kh][kw]
__global__ void dc_pack_w(const int* __restrict__ wt, unsigned int* __restrict__ wp) {
    const int tid = blockIdx.x * 256 + threadIdx.x;  // < 147456
    const int jq = tid & 3;
    const int l  = (tid >> 2) & 63;
    const int kb = (tid >> 8) & 7;
    const int r  = tid >> 11;          // 0..71
    const int t  = r % 9;
    const int cb2 = r / 9;             // 0..7
    const int co  = cb2 * 32 + (l & 31);
    const int ci0 = kb * 32 + (l >> 5) * 16 + jq * 4;
    const int kh = t / 3, kw = t - kh * 3;
    unsigned v = 0;
    #pragma unroll
    for (int k = 0; k < 4; ++k) {
        unsigned b = (unsigned)wt[((co * C_IN + ci0 + k) * 3 + kh) * 3 + kw];
        v |= (b & 0xff) << (8 * k);
    }
    wp[tid] = v;
}

// ---------- main kernel: implicit GEMM, no LDS ----------
// grid = (spatial_chunk/256) * 2; out pre-offset by n0*OUT_NSTR
__global__ __launch_bounds__(256, 2) void dc_mfma(const char* __restrict__ x8,
                                                  const char* __restrict__ wp,
                                                  int* __restrict__ out) {
    const int tid = threadIdx.x;
    const int l = tid & 63, wid = tid >> 6;
    const int lane31 = l & 31, hi = l >> 5;
    const int bid = blockIdx.x;
    const int cohalf = bid & 1, sb = bid >> 1;      // adjacent blocks share s-tile (L2 reuse of X)
    const int cg = wid & 1, sg = wid >> 1;
    const int cobase = cohalf * 128 + cg * 64;
    const int sbase  = sb * 256 + sg * 128;

    // per n-fragment (spatial) setup
    const char* xp[4];
    int outb[4];
    #pragma unroll
    for (int ni = 0; ni < 4; ++ni) {
        const int s = sbase + ni * 32 + lane31;
        const int n = s / HW2;                   // local image index within chunk
        const int hw = s - n * HW2;
        const int h = hw / HWDIM;
        const int w = hw - h * HWDIM;
        xp[ni] = x8 + (size_t)n * XP_NSTR + (h + 1) * XP_HSTR + (w + 1) * 256 + hi * 16;
        outb[ni] = n * OUT_NSTR + hw;
    }

    const int cb2_0 = cohalf * 4 + cg * 2;
    const char* wbase0 = wp + cb2_0 * WP_CB2STR + l * 16;

    v16i acc[2][4] = {};

    for (int t = 0; t < 9; ++t) {
        const int dh = t / 3 - 1, dw = t - (t / 3) * 3 - 1;
        const int xoff = (dh * 58 + dw) * 256;
        const char* xt0 = xp[0] + xoff;
        const char* xt1 = xp[1] + xoff;
        const char* xt2 = xp[2] + xoff;
        const char* xt3 = xp[3] + xoff;
        const char* wt0 = wbase0 + t * 8192;
        const char* wt1 = wt0 + WP_CB2STR;

        #pragma unroll
        for (int kb = 0; kb < 8; ++kb) {
            const v4i a0 = *(const v4i*)(wt0 + kb * 1024);
            const v4i a1 = *(const v4i*)(wt1 + kb * 1024);
            const v4i b0 = *(const v4i*)(xt0 + kb * 32);
            const v4i b1 = *(const v4i*)(xt1 + kb * 32);
            const v4i b2 = *(const v4i*)(xt2 + kb * 32);
            const v4i b3 = *(const v4i*)(xt3 + kb * 32);
            acc[0][0] = __builtin_amdgcn_mfma_i32_32x32x32_i8(a0, b0, acc[0][0], 0, 0, 0);
            acc[0][1] = __builtin_amdgcn_mfma_i32_32x32x32_i8(a0, b1, acc[0][1], 0, 0, 0);
            acc[0][2] = __builtin_amdgcn_mfma_i32_32x32x32_i8(a0, b2, acc[0][2], 0, 0, 0);
            acc[0][3] = __builtin_amdgcn_mfma_i32_32x32x32_i8(a0, b3, acc[0][3], 0, 0, 0);
            acc[1][0] = __builtin_amdgcn_mfma_i32_32x32x32_i8(a1, b0, acc[1][0], 0, 0, 0);
            acc[1][1] = __builtin_amdgcn_mfma_i32_32x32x32_i8(a1, b1, acc[1][1], 0, 0, 0);
            acc[1][2] = __builtin_amdgcn_mfma_i32_32x32x32_i8(a1, b2, acc[1][2], 0, 0, 0);
            acc[1][3] = __builtin_amdgcn_mfma_i32_32x32x32_i8(a1, b3, acc[1][3], 0, 0, 0);
        }
    }

    // C/D: col = lane&31 (spatial, contiguous), row = (r&3)+8*(r>>2)+4*hi (co)
    #pragma unroll
    for (int mi = 0; mi < 2; ++mi) {
        #pragma unroll
        for (int ni = 0; ni < 4; ++ni) {
            const v16i c = acc[mi][ni];
            int* ob = out + outb[ni] + (cobase + mi * 32 + 4 * hi) * HW2;
            #pragma unroll
            for (int r = 0; r < 16; ++r) {
                ob[((r & 3) + 8 * (r >> 2)) * HW2] = c[r];
            }
        }
    }
}

// ---------- fallback: direct conv (correct, slow) ----------
__global__ void dc_naive(const int* __restrict__ x, const int* __restrict__ wt,
                         int* __restrict__ out) {
    const int idx = blockIdx.x * 256 + threadIdx.x;
    if (idx >= OUT_TOT) return;
    const int w = idx % HWDIM;
    const int h = (idx / HWDIM) % HWDIM;
    const int co = (idx / HW2) & 255;
    const int n = idx / OUT_NSTR;
    const int* xn = x + n * OUT_NSTR;
    const int* wo = wt + co * (C_IN * 9);
    int acc = 0;
    for (int ci = 0; ci < C_IN; ++ci) {
        const int* xc = xn + ci * HW2;
        const int* wc = wo + ci * 9;
        #pragma unroll
        for (int kh = 0; kh < 3; ++kh) {
            const int hh = h + kh - 1;
            if ((unsigned)hh >= HWDIM) continue;
            #pragma unroll
            for (int kw = 0; kw < 3; ++kw) {
                const int ww = w + kw - 1;
                if ((unsigned)ww >= HWDIM) continue;
                acc += xc[hh * HWDIM + ww] * wc[kh * 3 + kw];
            }
        }
    }
    out[idx] = acc;
}

extern "C" void kernel_launch(void* const* d_in, const int* in_sizes, int n_in,
                              void* d_out, int out_size, void* d_ws, size_t ws_size,
                              hipStream_t stream) {
    const int* x  = (const int*)d_in[0];
    const int* wt = (const int*)d_in[1];
    int* out = (int*)d_out;

    // pick largest image-chunk that fits the workspace (deterministic per run)
    int chunk = 0;
    const int cand[4] = {32, 16, 8, 4};
    for (int i = 0; i < 4; ++i) {
        if ((size_t)cand[i] * XP_NSTR + WP_BYTES <= ws_size) { chunk = cand[i]; break; }
    }

    if (chunk > 0) {
        char* x8 = (char*)d_ws;
        unsigned int* wp = (unsigned int*)((char*)d_ws + (size_t)chunk * XP_NSTR);
        hipMemsetAsync(x8, 0, (size_t)chunk * XP_NSTR, stream);   // zero halo once
        hipLaunchKernelGGL(dc_pack_w, dim3(576), dim3(256), 0, stream, wt, wp);
        for (int n0 = 0; n0 < N_IMG; n0 += chunk) {
            hipLaunchKernelGGL(dc_x_to_nhwc, dim3(chunk * HWDIM), dim3(256), 0, stream,
                               x, (unsigned int*)x8, n0);
            const int sblocks = (chunk * HW2) / 256;              // chunk%4==0 -> exact
            hipLaunchKernelGGL(dc_mfma, dim3(sblocks * 2), dim3(256), 0, stream,
                               (const char*)x8, (const char*)wp,
                               out + (size_t)n0 * OUT_NSTR);
        }
        return;
    }

    hipLaunchKernelGGL(dc_naive, dim3((OUT_TOT + 255) / 256), dim3(256), 0, stream,
                       x, wt, out);
}

// Round 3
// 197.571 us; speedup vs baseline: 90.6436x; 1.0172x over previous
//
#include <hip/hip_runtime.h>

typedef int v4i  __attribute__((ext_vector_type(4)));
typedef int v16i __attribute__((ext_vector_type(16)));

// ---- problem constants ----
#define N_IMG   32
#define C_IN    256
#define C_OUT   256
#define HWDIM   56
#define HW2     3136            // 56*56
#define OUT_TOT 25690112        // 32*256*56*56
#define OUT_NSTR 802816         // 256*3136

// x8p padded NHWC int8 per image: [58][58][256] bytes
#define XP_HSTR 14848           // 58*256
#define XP_NSTR 861184          // 58*58*256 bytes per image
// packed weights: [cb2:8][tap:9][kb:8][lane:64][16B]
#define WP_CB2STR 73728         // 9*8*1024
#define WP_BYTES  589824ull

// ---------- pre-pass A: x NCHW int32 -> NHWC int8 with zero halo ----------
__global__ void dc_x_to_nhwc(const int* __restrict__ x, unsigned int* __restrict__ x8,
                             int n0) {
    __shared__ unsigned int lds[64 * 65];   // [w:64][cig:64] +1-dword pad per row
    const int t = threadIdx.x;
    const int w = t & 63, q = t >> 6;
    const int nl = blockIdx.x / HWDIM, h = blockIdx.x % HWDIM;

    if (w < HWDIM) {
        const int* xb = x + (size_t)(n0 + nl) * OUT_NSTR + h * HWDIM + w;
        #pragma unroll
        for (int it = 0; it < 16; ++it) {
            const int cg4 = q * 16 + it;
            const int ci0 = cg4 * 4;
            unsigned v  =  ((unsigned)xb[(ci0 + 0) * HW2] & 0xff);
            v |= ((unsigned)xb[(ci0 + 1) * HW2] & 0xff) << 8;
            v |= ((unsigned)xb[(ci0 + 2) * HW2] & 0xff) << 16;
            v |= ((unsigned)xb[(ci0 + 3) * HW2] & 0xff) << 24;
            lds[w * 65 + cg4] = v;
        }
    }
    __syncthreads();
    unsigned int* ob = x8 + (nl * (XP_NSTR / 4) + (h + 1) * (XP_HSTR / 4) + 64);
    #pragma unroll
    for (int it = 0; it < 14; ++it) {
        const int f = it * 256 + t;
        const int w2 = f >> 6, cg = f & 63;
        if (w2 < HWDIM) ob[w2 * 64 + cg] = lds[w2 * 65 + cg];
    }
}

// ---------- pre-pass B: pack weights into per-lane fragment order ----------
__global__ void dc_pack_w(const int* __restrict__ wt, unsigned int* __restrict__ wp) {
    const int tid = blockIdx.x * 256 + threadIdx.x;  // < 147456
    const int jq = tid & 3;
    const int l  = (tid >> 2) & 63;
    const int kb = (tid >> 8) & 7;
    const int r  = tid >> 11;          // 0..71
    const int t  = r % 9;
    const int cb2 = r / 9;             // 0..7
    const int co  = cb2 * 32 + (l & 31);
    const int ci0 = kb * 32 + (l >> 5) * 16 + jq * 4;
    const int kh = t / 3, kw = t - kh * 3;
    unsigned v = 0;
    #pragma unroll
    for (int k = 0; k < 4; ++k) {
        unsigned b = (unsigned)wt[((co * C_IN + ci0 + k) * 3 + kh) * 3 + kw];
        v |= (b & 0xff) << (8 * k);
    }
    wp[tid] = v;
}

// ---------- main kernel: implicit GEMM, no LDS, 64co x 64s per wave ----------
// block = 128co x 128s (4 waves: cg x sg). nwg = (S_chunk/128)*2.
__global__ __launch_bounds__(256, 4) void dc_mfma(const char* __restrict__ x8,
                                                  const char* __restrict__ wp,
                                                  int* __restrict__ out, int nwg) {
    // bijective XCD swizzle (m204): consecutive wgids share the s-tile
    const int bid = blockIdx.x;
    const int q = nwg >> 3, r = nwg & 7;
    const int xcd = bid & 7, bidx = bid >> 3;
    const int wgid = (xcd < r ? xcd * (q + 1) : r * (q + 1) + (xcd - r) * q) + bidx;

    const int cohalf = wgid & 1, sb = wgid >> 1;

    const int tid = threadIdx.x;
    const int l = tid & 63, wid = tid >> 6;
    const int lane31 = l & 31, hi = l >> 5;
    const int cg = wid & 1, sg = wid >> 1;

    const int sbase = sb * 128 + sg * 64;

    // per s-fragment setup (2 frags of 32 spatial)
    const char* xp0;
    const char* xp1;
    int outb[2];
    #pragma unroll
    for (int ni = 0; ni < 2; ++ni) {
        const int s = sbase + ni * 32 + lane31;
        const int n = s / HW2;
        const int hw = s - n * HW2;
        const int h = hw / HWDIM;
        const int w = hw - h * HWDIM;
        const char* p = x8 + (size_t)n * XP_NSTR + (h + 1) * XP_HSTR + (w + 1) * 256 + hi * 16;
        if (ni == 0) xp0 = p; else xp1 = p;
        outb[ni] = n * OUT_NSTR + hw;
    }

    const int cb2_0 = cohalf * 4 + cg * 2;
    const char* wb0 = wp + cb2_0 * WP_CB2STR + l * 16;
    const char* wb1 = wb0 + WP_CB2STR;

    // tap spatial offsets in padded NHWC bytes
    const int xoffs[9] = {
        (-58 - 1) * 256, (-58) * 256, (-58 + 1) * 256,
        (-1) * 256,      0,           (1) * 256,
        (58 - 1) * 256,  (58) * 256,  (58 + 1) * 256
    };

    v16i acc[2][2] = {};
    v4i a0[2], a1[2], b0[2], b1[2];

    // prime iteration 0 (t=0, kb=0)
    a0[0] = *(const v4i*)(wb0);
    a1[0] = *(const v4i*)(wb1);
    b0[0] = *(const v4i*)(xp0 + xoffs[0]);
    b1[0] = *(const v4i*)(xp1 + xoffs[0]);

    #pragma unroll
    for (int i = 0; i < 72; ++i) {
        const int cur = i & 1, nxt = cur ^ 1;
        if (i < 71) {
            const int j = i + 1;
            const int t = j >> 3, kb = j & 7;
            const int xo = xoffs[t] + kb * 32;
            a0[nxt] = *(const v4i*)(wb0 + j * 1024);
            a1[nxt] = *(const v4i*)(wb1 + j * 1024);
            b0[nxt] = *(const v4i*)(xp0 + xo);
            b1[nxt] = *(const v4i*)(xp1 + xo);
        }
        acc[0][0] = __builtin_amdgcn_mfma_i32_32x32x32_i8(a0[cur], b0[cur], acc[0][0], 0, 0, 0);
        acc[0][1] = __builtin_amdgcn_mfma_i32_32x32x32_i8(a0[cur], b1[cur], acc[0][1], 0, 0, 0);
        acc[1][0] = __builtin_amdgcn_mfma_i32_32x32x32_i8(a1[cur], b0[cur], acc[1][0], 0, 0, 0);
        acc[1][1] = __builtin_amdgcn_mfma_i32_32x32x32_i8(a1[cur], b1[cur], acc[1][1], 0, 0, 0);
    }

    // C/D: col = lane&31 (spatial), row = (r&3)+8*(r>>2)+4*hi (co)
    #pragma unroll
    for (int mi = 0; mi < 2; ++mi) {
        #pragma unroll
        for (int ni = 0; ni < 2; ++ni) {
            const v16i c = acc[mi][ni];
            int* ob = out + outb[ni] + (cohalf * 128 + cg * 64 + mi * 32 + 4 * hi) * HW2;
            #pragma unroll
            for (int rr = 0; rr < 16; ++rr) {
                ob[((rr & 3) + 8 * (rr >> 2)) * HW2] = c[rr];
            }
        }
    }
}

// ---------- fallback: direct conv (correct, slow) ----------
__global__ void dc_naive(const int* __restrict__ x, const int* __restrict__ wt,
                         int* __restrict__ out) {
    const int idx = blockIdx.x * 256 + threadIdx.x;
    if (idx >= OUT_TOT) return;
    const int w = idx % HWDIM;
    const int h = (idx / HWDIM) % HWDIM;
    const int co = (idx / HW2) & 255;
    const int n = idx / OUT_NSTR;
    const int* xn = x + n * OUT_NSTR;
    const int* wo = wt + co * (C_IN * 9);
    int acc = 0;
    for (int ci = 0; ci < C_IN; ++ci) {
        const int* xc = xn + ci * HW2;
        const int* wc = wo + ci * 9;
        #pragma unroll
        for (int kh = 0; kh < 3; ++kh) {
            const int hh = h + kh - 1;
            if ((unsigned)hh >= HWDIM) continue;
            #pragma unroll
            for (int kw = 0; kw < 3; ++kw) {
                const int ww = w + kw - 1;
                if ((unsigned)ww >= HWDIM) continue;
                acc += xc[hh * HWDIM + ww] * wc[kh * 3 + kw];
            }
        }
    }
    out[idx] = acc;
}

extern "C" void kernel_launch(void* const* d_in, const int* in_sizes, int n_in,
                              void* d_out, int out_size, void* d_ws, size_t ws_size,
                              hipStream_t stream) {
    const int* x  = (const int*)d_in[0];
    const int* wt = (const int*)d_in[1];
    int* out = (int*)d_out;

    int chunk = 0;
    const int cand[4] = {32, 16, 8, 4};
    for (int i = 0; i < 4; ++i) {
        if ((size_t)cand[i] * XP_NSTR + WP_BYTES <= ws_size) { chunk = cand[i]; break; }
    }

    if (chunk > 0) {
        char* x8 = (char*)d_ws;
        unsigned int* wp = (unsigned int*)((char*)d_ws + (size_t)chunk * XP_NSTR);
        hipMemsetAsync(x8, 0, (size_t)chunk * XP_NSTR, stream);   // zero halo once
        hipLaunchKernelGGL(dc_pack_w, dim3(576), dim3(256), 0, stream, wt, wp);
        for (int n0 = 0; n0 < N_IMG; n0 += chunk) {
            hipLaunchKernelGGL(dc_x_to_nhwc, dim3(chunk * HWDIM), dim3(256), 0, stream,
                               x, (unsigned int*)x8, n0);
            const int nwg = ((chunk * HW2) / 128) * 2;            // chunk even -> exact
            hipLaunchKernelGGL(dc_mfma, dim3(nwg), dim3(256), 0, stream,
                               (const char*)x8, (const char*)wp,
                               out + (size_t)n0 * OUT_NSTR, nwg);
        }
        return;
    }

    hipLaunchKernelGGL(dc_naive, dim3((OUT_TOT + 255) / 256), dim3(256), 0, stream,
                       x, wt, out);
}

// Round 4
// 148.620 us; speedup vs baseline: 120.4984x; 1.3294x over previous
//
#include <hip/hip_runtime.h>

typedef int v4i  __attribute__((ext_vector_type(4)));
typedef int v16i __attribute__((ext_vector_type(16)));

// ---- problem constants ----
#define N_IMG   32
#define C_IN    256
#define HWDIM   56
#define HW2     3136            // 56*56
#define OUT_TOT 25690112        // 32*256*56*56
#define OUT_NSTR 802816         // 256*3136

// padded NHWC int8, PXB bytes per pixel (256 data + 16 pad for LDS banking)
#define PXB     272
#define PPI     3364            // 58*58 padded pixels per image
#define XP_IMG  915008          // PPI*PXB bytes per image
#define XP_SLACK 69632          // 256*PXB staging overrun slack
// packed weights: [cb2:8][tap:9][kb:8][lane:64][16B]
#define WP_CB2STR 73728
#define WP_BYTES  589824ull

#define STAGE_PX 256
#define LDSB    69632           // STAGE_PX*PXB

// ---------- pre-pass A: x NCHW int32 -> padded NHWC int8 (272B/pixel) ----------
__global__ void dc_x_to_nhwc(const int* __restrict__ x, unsigned int* __restrict__ x8,
                             int n0) {
    __shared__ unsigned int lds[64 * 65];
    const int t = threadIdx.x;
    const int w = t & 63, q = t >> 6;
    const int nl = blockIdx.x / HWDIM, h = blockIdx.x % HWDIM;

    if (w < HWDIM) {
        const int* xb = x + (size_t)(n0 + nl) * OUT_NSTR + h * HWDIM + w;
        #pragma unroll
        for (int it = 0; it < 16; ++it) {
            const int cg4 = q * 16 + it;
            const int ci0 = cg4 * 4;
            unsigned v  =  ((unsigned)xb[(ci0 + 0) * HW2] & 0xff);
            v |= ((unsigned)xb[(ci0 + 1) * HW2] & 0xff) << 8;
            v |= ((unsigned)xb[(ci0 + 2) * HW2] & 0xff) << 16;
            v |= ((unsigned)xb[(ci0 + 3) * HW2] & 0xff) << 24;
            lds[w * 65 + cg4] = v;
        }
    }
    __syncthreads();
    // write x8[nl][(h+1)*58 + (w2+1)] pixel block, dwords 0..63 of 68
    unsigned int* ob = x8 + (size_t)nl * (PPI * (PXB / 4)) + ((h + 1) * 58 + 1) * (PXB / 4);
    #pragma unroll
    for (int it = 0; it < 14; ++it) {
        const int f = it * 256 + t;
        const int w2 = f >> 6, cg = f & 63;
        if (w2 < HWDIM) ob[w2 * (PXB / 4) + cg] = lds[w2 * 65 + cg];
    }
}

// ---------- pre-pass B: pack weights into per-lane fragment order ----------
__global__ void dc_pack_w(const int* __restrict__ wt, unsigned int* __restrict__ wp) {
    const int tid = blockIdx.x * 256 + threadIdx.x;  // < 147456
    const int jq = tid & 3;
    const int l  = (tid >> 2) & 63;
    const int kb = (tid >> 8) & 7;
    const int r  = tid >> 11;          // 0..71
    const int t  = r % 9;
    const int cb2 = r / 9;             // 0..7
    const int co  = cb2 * 32 + (l & 31);
    const int ci0 = kb * 32 + (l >> 5) * 16 + jq * 4;
    const int kh = t / 3, kw = t - kh * 3;
    unsigned v = 0;
    #pragma unroll
    for (int k = 0; k < 4; ++k) {
        unsigned b = (unsigned)wt[((co * C_IN + ci0 + k) * 3 + kh) * 3 + kw];
        v |= (b & 0xff) << (8 * k);
    }
    wp[tid] = v;
}

__device__ __forceinline__ void gll16(const char* g, char* l) {
    __builtin_amdgcn_global_load_lds(
        (const __attribute__((address_space(1))) unsigned int*)g,
        (__attribute__((address_space(3))) unsigned int*)l, 16, 0, 0);
}

// ---------- main kernel: X staged once in LDS, barrier-free K-loop ----------
// block = 128co x 128s (4 waves: cg x sg), dynamic LDS = LDSB
__global__ __launch_bounds__(256, 2) void dc_mfma(const char* __restrict__ x8,
                                                  const char* __restrict__ wp,
                                                  int* __restrict__ out, int nwg) {
    extern __shared__ __align__(16) char xs[];

    // bijective XCD swizzle (m204): consecutive wgids land on the same XCD
    const int bid = blockIdx.x;
    const int q = nwg >> 3, r = nwg & 7;
    const int xcd = bid & 7, bidx = bid >> 3;
    const int wgid = (xcd < r ? xcd * (q + 1) : r * (q + 1) + (xcd - r) * q) + bidx;

    const int nl = wgid / 50;
    const int rem = wgid - nl * 50;
    const int st = rem >> 1, cohalf = rem & 1;

    const int tid = threadIdx.x;
    const int l = tid & 63, wid = tid >> 6;
    const int lane31 = l & 31, hi = l >> 5;
    const int cg = wid & 1, sg = wid >> 1;

    // stage window: pixels [p0, p0+256) of this image (contiguous bytes)
    const int hw0 = st * 128;
    const int p0 = (hw0 / HWDIM + 1) * 58 + (hw0 % HWDIM) + 1 - 59;
    const char* gsrc = x8 + (size_t)nl * XP_IMG + (size_t)p0 * PXB;

    #pragma unroll
    for (int c = 0; c < 17; ++c) {              // 17*256*16 = 69632 bytes
        const int off = (c * 256 + tid) * 16;
        gll16(gsrc + off, xs + off);
    }

    // per-s-fragment setup (2 frags of 32 spatial) while loads fly
    int pxb[2], outb[2];
    bool val[2];
    #pragma unroll
    for (int ni = 0; ni < 2; ++ni) {
        int hw = hw0 + sg * 64 + ni * 32 + lane31;
        val[ni] = (hw < HW2);
        if (!val[ni]) hw = HW2 - 1;
        const int p = (hw / HWDIM + 1) * 58 + (hw % HWDIM) + 1;
        pxb[ni] = (p - p0) * PXB + hi * 16;
        outb[ni] = nl * OUT_NSTR + hw;
    }

    const char* wb0 = wp + (cohalf * 4 + cg * 2) * WP_CB2STR + l * 16;
    const char* wb1 = wb0 + WP_CB2STR;

    __syncthreads();                            // stage complete

    const int xsh[9] = {
        -59 * PXB, -58 * PXB, -57 * PXB,
        -1 * PXB,   0,          1 * PXB,
        57 * PXB,  58 * PXB,  59 * PXB
    };

    v16i acc[2][2] = {};

    #pragma unroll
    for (int t = 0; t < 9; ++t) {
        #pragma unroll
        for (int kb = 0; kb < 8; ++kb) {
            const int j = t * 8 + kb;
            const v4i a0 = *(const v4i*)(wb0 + j * 1024);
            const v4i a1 = *(const v4i*)(wb1 + j * 1024);
            const v4i b0 = *(const v4i*)(xs + (pxb[0] + xsh[t] + kb * 32));
            const v4i b1 = *(const v4i*)(xs + (pxb[1] + xsh[t] + kb * 32));
            acc[0][0] = __builtin_amdgcn_mfma_i32_32x32x32_i8(a0, b0, acc[0][0], 0, 0, 0);
            acc[0][1] = __builtin_amdgcn_mfma_i32_32x32x32_i8(a0, b1, acc[0][1], 0, 0, 0);
            acc[1][0] = __builtin_amdgcn_mfma_i32_32x32x32_i8(a1, b0, acc[1][0], 0, 0, 0);
            acc[1][1] = __builtin_amdgcn_mfma_i32_32x32x32_i8(a1, b1, acc[1][1], 0, 0, 0);
        }
    }

    // C/D: col = lane&31 (spatial), row = (r&3)+8*(r>>2)+4*hi (co)
    #pragma unroll
    for (int mi = 0; mi < 2; ++mi) {
        #pragma unroll
        for (int ni = 0; ni < 2; ++ni) {
            if (!val[ni]) continue;
            const v16i c = acc[mi][ni];
            int* ob = out + outb[ni] + (cohalf * 128 + cg * 64 + mi * 32 + 4 * hi) * HW2;
            #pragma unroll
            for (int rr = 0; rr < 16; ++rr) {
                ob[((rr & 3) + 8 * (rr >> 2)) * HW2] = c[rr];
            }
        }
    }
}

// ---------- fallback: direct conv (correct, slow) ----------
__global__ void dc_naive(const int* __restrict__ x, const int* __restrict__ wt,
                         int* __restrict__ out) {
    const int idx = blockIdx.x * 256 + threadIdx.x;
    if (idx >= OUT_TOT) return;
    const int w = idx % HWDIM;
    const int h = (idx / HWDIM) % HWDIM;
    const int co = (idx / HW2) & 255;
    const int n = idx / OUT_NSTR;
    const int* xn = x + n * OUT_NSTR;
    const int* wo = wt + co * (C_IN * 9);
    int acc = 0;
    for (int ci = 0; ci < C_IN; ++ci) {
        const int* xc = xn + ci * HW2;
        const int* wc = wo + ci * 9;
        #pragma unroll
        for (int kh = 0; kh < 3; ++kh) {
            const int hh = h + kh - 1;
            if ((unsigned)hh >= HWDIM) continue;
            #pragma unroll
            for (int kw = 0; kw < 3; ++kw) {
                const int ww = w + kw - 1;
                if ((unsigned)ww >= HWDIM) continue;
                acc += xc[hh * HWDIM + ww] * wc[kh * 3 + kw];
            }
        }
    }
    out[idx] = acc;
}

extern "C" void kernel_launch(void* const* d_in, const int* in_sizes, int n_in,
                              void* d_out, int out_size, void* d_ws, size_t ws_size,
                              hipStream_t stream) {
    const int* x  = (const int*)d_in[0];
    const int* wt = (const int*)d_in[1];
    int* out = (int*)d_out;

    int chunk = 0;
    const int cand[4] = {32, 16, 8, 4};
    for (int i = 0; i < 4; ++i) {
        if ((size_t)cand[i] * XP_IMG + XP_SLACK + WP_BYTES <= ws_size) { chunk = cand[i]; break; }
    }

    if (chunk > 0) {
        char* x8 = (char*)d_ws;
        const size_t x8_bytes = (size_t)chunk * XP_IMG + XP_SLACK;
        unsigned int* wp = (unsigned int*)(x8 + x8_bytes);
        hipMemsetAsync(x8, 0, x8_bytes, stream);                  // zero halo + pads once
        hipLaunchKernelGGL(dc_pack_w, dim3(576), dim3(256), 0, stream, wt, wp);
        for (int n0 = 0; n0 < N_IMG; n0 += chunk) {
            hipLaunchKernelGGL(dc_x_to_nhwc, dim3(chunk * HWDIM), dim3(256), 0, stream,
                               x, (unsigned int*)x8, n0);
            const int nwg = chunk * 50;                           // 25 tiles * 2 cohalf per image
            hipLaunchKernelGGL(dc_mfma, dim3(nwg), dim3(256), LDSB, stream,
                               (const char*)x8, (const char*)wp,
                               out + (size_t)n0 * OUT_NSTR, nwg);
        }
        return;
    }

    hipLaunchKernelGGL(dc_naive, dim3((OUT_TOT + 255) / 256), dim3(256), 0, stream,
                       x, wt, out);
}

// Round 5
// 121.368 us; speedup vs baseline: 147.5555x; 1.2245x over previous
//
#include <hip/hip_runtime.h>

typedef int v4i  __attribute__((ext_vector_type(4)));
typedef int v16i __attribute__((ext_vector_type(16)));

// ---- problem constants ----
#define N_IMG   32
#define C_IN    256
#define HWDIM   56
#define HW2     3136            // 56*56
#define OUT_TOT 25690112        // 32*256*56*56
#define OUT_NSTR 802816         // 256*3136

// padded NHWC int8, PXB bytes per pixel (256 data + 16 pad; 2-way b128 floor)
#define PXB     272
#define PPI     3364            // 58*58 padded pixels per image
#define XP_IMG  915008          // PPI*PXB bytes per image
#define XP_SLACK 69632          // 256*PXB staging overrun slack
// packed weights: [cb2:8][tap:9][kb:8][lane:64][16B]
#define WP_CB2STR 73728
#define WP_BYTES  589824ull

#define STAGE_PX 256
#define LDSB    69632           // STAGE_PX*PXB

// ---------- pre-pass A: x NCHW int32 -> padded NHWC int8 (272B/pixel) ----------
__global__ void dc_x_to_nhwc(const int* __restrict__ x, unsigned int* __restrict__ x8,
                             int n0) {
    __shared__ unsigned int lds[64 * 65];
    const int t = threadIdx.x;
    const int w = t & 63, q = t >> 6;
    const int nl = blockIdx.x / HWDIM, h = blockIdx.x % HWDIM;

    if (w < HWDIM) {
        const int* xb = x + (size_t)(n0 + nl) * OUT_NSTR + h * HWDIM + w;
        #pragma unroll
        for (int it = 0; it < 16; ++it) {
            const int cg4 = q * 16 + it;
            const int ci0 = cg4 * 4;
            unsigned v  =  ((unsigned)xb[(ci0 + 0) * HW2] & 0xff);
            v |= ((unsigned)xb[(ci0 + 1) * HW2] & 0xff) << 8;
            v |= ((unsigned)xb[(ci0 + 2) * HW2] & 0xff) << 16;
            v |= ((unsigned)xb[(ci0 + 3) * HW2] & 0xff) << 24;
            lds[w * 65 + cg4] = v;
        }
    }
    __syncthreads();
    unsigned int* ob = x8 + (size_t)nl * (PPI * (PXB / 4)) + ((h + 1) * 58 + 1) * (PXB / 4);
    #pragma unroll
    for (int it = 0; it < 14; ++it) {
        const int f = it * 256 + t;
        const int w2 = f >> 6, cg = f & 63;
        if (w2 < HWDIM) ob[w2 * (PXB / 4) + cg] = lds[w2 * 65 + cg];
    }
}

// ---------- pre-pass B: pack weights into per-lane fragment order ----------
__global__ void dc_pack_w(const int* __restrict__ wt, unsigned int* __restrict__ wp) {
    const int tid = blockIdx.x * 256 + threadIdx.x;  // < 147456
    const int jq = tid & 3;
    const int l  = (tid >> 2) & 63;
    const int kb = (tid >> 8) & 7;
    const int r  = tid >> 11;          // 0..71
    const int t  = r % 9;
    const int cb2 = r / 9;             // 0..7
    const int co  = cb2 * 32 + (l & 31);
    const int ci0 = kb * 32 + (l >> 5) * 16 + jq * 4;
    const int kh = t / 3, kw = t - kh * 3;
    unsigned v = 0;
    #pragma unroll
    for (int k = 0; k < 4; ++k) {
        unsigned b = (unsigned)wt[((co * C_IN + ci0 + k) * 3 + kh) * 3 + kw];
        v |= (b & 0xff) << (8 * k);
    }
    wp[tid] = v;
}

__device__ __forceinline__ void gll16(const char* g, char* l) {
    __builtin_amdgcn_global_load_lds(
        (const __attribute__((address_space(1))) unsigned int*)g,
        (__attribute__((address_space(3))) unsigned int*)l, 16, 0, 0);
}

// ---------- main kernel: 256co x 128s per block, X in LDS, deep W prefetch ----
// 4 waves, each 64co x 128s (acc[2][4]); barrier-free K-loop after one stage.
__global__ __launch_bounds__(256, 2) void dc_mfma(const char* __restrict__ x8,
                                                  const char* __restrict__ wp,
                                                  int* __restrict__ out, int nwg) {
    extern __shared__ __align__(16) char xs[];

    // bijective XCD swizzle (m204)
    const int bid = blockIdx.x;
    const int q = nwg >> 3, r = nwg & 7;
    const int xcd = bid & 7, bidx = bid >> 3;
    const int wgid = (xcd < r ? xcd * (q + 1) : r * (q + 1) + (xcd - r) * q) + bidx;

    const int nl = wgid / 25, st = wgid - nl * 25;

    const int tid = threadIdx.x;
    const int l = tid & 63, wid = tid >> 6;
    const int lane31 = l & 31, hi = l >> 5;

    // stage window: pixels [p0, p0+256) of this image (contiguous bytes)
    const int hw0 = st * 128;
    const int p0 = (hw0 / HWDIM + 1) * 58 + (hw0 % HWDIM) + 1 - 59;
    const char* gsrc = x8 + (size_t)nl * XP_IMG + (size_t)p0 * PXB;

    #pragma unroll
    for (int c = 0; c < 17; ++c) {              // 17*256*16 = 69632 bytes
        const int off = (c * 256 + tid) * 16;
        gll16(gsrc + off, xs + off);
    }

    // per-s-fragment setup (4 frags of 32 spatial) while loads fly
    int pxb[4], outb[4];
    bool val[4];
    #pragma unroll
    for (int ni = 0; ni < 4; ++ni) {
        int hw = hw0 + ni * 32 + lane31;
        val[ni] = (hw < HW2);
        if (!val[ni]) hw = HW2 - 1;
        const int p = (hw / HWDIM + 1) * 58 + (hw % HWDIM) + 1;
        pxb[ni] = (p - p0) * PXB + hi * 16;
        outb[ni] = nl * OUT_NSTR + hw;
    }

    // wave wid owns co = wid*64 .. +63  (cb2 = wid*2, wid*2+1)
    const char* wb0 = wp + (wid * 2) * WP_CB2STR + l * 16;
    const char* wb1 = wb0 + WP_CB2STR;

    const int xsh[9] = {
        -59 * PXB, -58 * PXB, -57 * PXB,
        -1 * PXB,   0,          1 * PXB,
        57 * PXB,  58 * PXB,  59 * PXB
    };

    __syncthreads();                            // stage complete; no more barriers

    v16i acc[2][4] = {};
    v4i wa[3][2];                               // depth-2 W prefetch ring
    v4i xb[2][4];                               // depth-1 X prefetch ring

    wa[0][0] = *(const v4i*)(wb0);
    wa[0][1] = *(const v4i*)(wb1);
    wa[1][0] = *(const v4i*)(wb0 + 1024);
    wa[1][1] = *(const v4i*)(wb1 + 1024);
    #pragma unroll
    for (int ni = 0; ni < 4; ++ni)
        xb[0][ni] = *(const v4i*)(xs + pxb[ni] + xsh[0]);

    #pragma unroll
    for (int j = 0; j < 72; ++j) {              // j = tap*8 + kb; all idx static
        const int jc = j % 3;
        const int pc = j & 1;
        if (j + 2 < 72) {
            const int jn = (j + 2) % 3;
            wa[jn][0] = *(const v4i*)(wb0 + (j + 2) * 1024);
            wa[jn][1] = *(const v4i*)(wb1 + (j + 2) * 1024);
        }
        if (j + 1 < 72) {
            const int t1 = (j + 1) >> 3, kb1 = (j + 1) & 7;
            const int xo = xsh[t1] + kb1 * 32;
            #pragma unroll
            for (int ni = 0; ni < 4; ++ni)
                xb[pc ^ 1][ni] = *(const v4i*)(xs + pxb[ni] + xo);
        }
        #pragma unroll
        for (int mi = 0; mi < 2; ++mi) {
            #pragma unroll
            for (int ni = 0; ni < 4; ++ni) {
                acc[mi][ni] = __builtin_amdgcn_mfma_i32_32x32x32_i8(
                    wa[jc][mi], xb[pc][ni], acc[mi][ni], 0, 0, 0);
            }
        }
    }

    // C/D: col = lane&31 (spatial), row = (r&3)+8*(r>>2)+4*hi (co)
    #pragma unroll
    for (int mi = 0; mi < 2; ++mi) {
        #pragma unroll
        for (int ni = 0; ni < 4; ++ni) {
            if (!val[ni]) continue;
            const v16i c = acc[mi][ni];
            int* ob = out + outb[ni] + (wid * 64 + mi * 32 + 4 * hi) * HW2;
            #pragma unroll
            for (int rr = 0; rr < 16; ++rr) {
                ob[((rr & 3) + 8 * (rr >> 2)) * HW2] = c[rr];
            }
        }
    }
}

// ---------- fallback: direct conv (correct, slow) ----------
__global__ void dc_naive(const int* __restrict__ x, const int* __restrict__ wt,
                         int* __restrict__ out) {
    const int idx = blockIdx.x * 256 + threadIdx.x;
    if (idx >= OUT_TOT) return;
    const int w = idx % HWDIM;
    const int h = (idx / HWDIM) % HWDIM;
    const int co = (idx / HW2) & 255;
    const int n = idx / OUT_NSTR;
    const int* xn = x + n * OUT_NSTR;
    const int* wo = wt + co * (C_IN * 9);
    int acc = 0;
    for (int ci = 0; ci < C_IN; ++ci) {
        const int* xc = xn + ci * HW2;
        const int* wc = wo + ci * 9;
        #pragma unroll
        for (int kh = 0; kh < 3; ++kh) {
            const int hh = h + kh - 1;
            if ((unsigned)hh >= HWDIM) continue;
            #pragma unroll
            for (int kw = 0; kw < 3; ++kw) {
                const int ww = w + kw - 1;
                if ((unsigned)ww >= HWDIM) continue;
                acc += xc[hh * HWDIM + ww] * wc[kh * 3 + kw];
            }
        }
    }
    out[idx] = acc;
}

extern "C" void kernel_launch(void* const* d_in, const int* in_sizes, int n_in,
                              void* d_out, int out_size, void* d_ws, size_t ws_size,
                              hipStream_t stream) {
    const int* x  = (const int*)d_in[0];
    const int* wt = (const int*)d_in[1];
    int* out = (int*)d_out;

    int chunk = 0;
    const int cand[4] = {32, 16, 8, 4};
    for (int i = 0; i < 4; ++i) {
        if ((size_t)cand[i] * XP_IMG + XP_SLACK + WP_BYTES <= ws_size) { chunk = cand[i]; break; }
    }

    if (chunk > 0) {
        char* x8 = (char*)d_ws;
        const size_t x8_bytes = (size_t)chunk * XP_IMG + XP_SLACK;
        unsigned int* wp = (unsigned int*)(x8 + x8_bytes);
        hipMemsetAsync(x8, 0, x8_bytes, stream);                  // zero halo + pads once
        hipLaunchKernelGGL(dc_pack_w, dim3(576), dim3(256), 0, stream, wt, wp);
        for (int n0 = 0; n0 < N_IMG; n0 += chunk) {
            hipLaunchKernelGGL(dc_x_to_nhwc, dim3(chunk * HWDIM), dim3(256), 0, stream,
                               x, (unsigned int*)x8, n0);
            const int nwg = chunk * 25;                           // 25 tiles per image
            hipLaunchKernelGGL(dc_mfma, dim3(nwg), dim3(256), LDSB, stream,
                               (const char*)x8, (const char*)wp,
                               out + (size_t)n0 * OUT_NSTR, nwg);
        }
        return;
    }

    hipLaunchKernelGGL(dc_naive, dim3((OUT_TOT + 255) / 256), dim3(256), 0, stream,
                       x, wt, out);
}

// Round 6
// 95.992 us; speedup vs baseline: 186.5627x; 1.2644x over previous
//
#include <hip/hip_runtime.h>

typedef int v4i  __attribute__((ext_vector_type(4)));
typedef int v16i __attribute__((ext_vector_type(16)));

// ---- problem constants ----
#define N_IMG   32
#define C_IN    256
#define HWDIM   56
#define HW2     3136            // 56*56
#define OUT_TOT 25690112        // 32*256*56*56
#define OUT_NSTR 802816         // 256*3136

// padded NHWC int8, PXB bytes per pixel (256 data + 16 pad; b128 bank floor)
#define PXB     272
#define PPI     3364            // 58*58 padded pixels per image
#define XP_IMG  915008          // PPI*PXB bytes per image
// packed weights: [cb2:8][tap:9][kb:8][lane:64][16B]
#define WP_CB2STR 73728
#define WP_BYTES  589824ull

// main-kernel tiling: 256 spatial px per block, window = 59+265+1+59 = 384 px
#define S_TILE  256
#define TILES_PER_IMG 13        // ceil(3136/256)
#define WIN_PX  384
#define WIN_B   104448          // 384*272
#define XP_SLACK WIN_B

// ---------- pre-pass A: x NCHW int32 -> padded NHWC int8 (272B/pixel) ----------
__global__ void dc_x_to_nhwc(const int* __restrict__ x, unsigned int* __restrict__ x8,
                             int n0) {
    __shared__ unsigned int lds[64 * 65];
    const int t = threadIdx.x;
    const int w = t & 63, q = t >> 6;
    const int nl = blockIdx.x / HWDIM, h = blockIdx.x % HWDIM;

    if (w < HWDIM) {
        const int* xb = x + (size_t)(n0 + nl) * OUT_NSTR + h * HWDIM + w;
        #pragma unroll
        for (int it = 0; it < 16; ++it) {
            const int cg4 = q * 16 + it;
            const int ci0 = cg4 * 4;
            unsigned v  =  ((unsigned)xb[(ci0 + 0) * HW2] & 0xff);
            v |= ((unsigned)xb[(ci0 + 1) * HW2] & 0xff) << 8;
            v |= ((unsigned)xb[(ci0 + 2) * HW2] & 0xff) << 16;
            v |= ((unsigned)xb[(ci0 + 3) * HW2] & 0xff) << 24;
            lds[w * 65 + cg4] = v;
        }
    }
    __syncthreads();
    unsigned int* ob = x8 + (size_t)nl * (PPI * (PXB / 4)) + ((h + 1) * 58 + 1) * (PXB / 4);
    #pragma unroll
    for (int it = 0; it < 14; ++it) {
        const int f = it * 256 + t;
        const int w2 = f >> 6, cg = f & 63;
        if (w2 < HWDIM) ob[w2 * (PXB / 4) + cg] = lds[w2 * 65 + cg];
    }
}

// ---------- halo-ring zero (replaces full-workspace memset) ----------
__global__ void dc_halo(unsigned int* __restrict__ x8) {
    const int nl = blockIdx.x;
    const int t = threadIdx.x;          // 256 threads, 228 halo pixels
    if (t < 228) {
        int h, w;
        if (t < 58)       { h = 0;        w = t; }
        else if (t < 116) { h = 57;       w = t - 58; }
        else if (t < 172) { h = t - 115;  w = 0; }    // h = 1..56
        else              { h = t - 171;  w = 57; }   // h = 1..56
        unsigned int* p = x8 + ((size_t)nl * PPI + h * 58 + w) * (PXB / 4);
        #pragma unroll
        for (int i = 0; i < PXB / 4; ++i) p[i] = 0;
    }
}

// ---------- pre-pass B: pack weights into per-lane fragment order ----------
__global__ void dc_pack_w(const int* __restrict__ wt, unsigned int* __restrict__ wp) {
    const int tid = blockIdx.x * 256 + threadIdx.x;  // < 147456
    const int jq = tid & 3;
    const int l  = (tid >> 2) & 63;
    const int kb = (tid >> 8) & 7;
    const int r  = tid >> 11;          // 0..71
    const int t  = r % 9;
    const int cb2 = r / 9;             // 0..7
    const int co  = cb2 * 32 + (l & 31);
    const int ci0 = kb * 32 + (l >> 5) * 16 + jq * 4;
    const int kh = t / 3, kw = t - kh * 3;
    unsigned v = 0;
    #pragma unroll
    for (int k = 0; k < 4; ++k) {
        unsigned b = (unsigned)wt[((co * C_IN + ci0 + k) * 3 + kh) * 3 + kw];
        v |= (b & 0xff) << (8 * k);
    }
    wp[tid] = v;
}

__device__ __forceinline__ void gll16(const char* g, char* l) {
    __builtin_amdgcn_global_load_lds(
        (const __attribute__((address_space(1))) unsigned int*)g,
        (__attribute__((address_space(3))) unsigned int*)l, 16, 0, 0);
}

// ---------- main kernel: 256co x 256s per block (512 thr, 8 waves co4 x s2) --
// wave = 64co x 128s (acc[2][4]); X staged once in LDS; barrier-free K-loop.
__global__ __launch_bounds__(512, 2) void dc_mfma(const char* __restrict__ x8,
                                                  const char* __restrict__ wp,
                                                  int* __restrict__ out, int nwg) {
    extern __shared__ __align__(16) char xs[];

    // bijective XCD swizzle (m204)
    const int bid = blockIdx.x;
    const int q = nwg >> 3, r = nwg & 7;
    const int xcd = bid & 7, bidx = bid >> 3;
    const int wgid = (xcd < r ? xcd * (q + 1) : r * (q + 1) + (xcd - r) * q) + bidx;

    const int nl = wgid / TILES_PER_IMG, st = wgid - nl * TILES_PER_IMG;

    const int tid = threadIdx.x;
    const int l = tid & 63, wid = tid >> 6;
    const int lane31 = l & 31, hi = l >> 5;
    const int cow = wid & 3, sgw = wid >> 2;      // co-group (64co), s-group (128s)

    // stage window: pixels [p0, p0+384) of this image (contiguous bytes)
    const int hw0 = st * S_TILE;
    const int p0 = (hw0 / HWDIM + 1) * 58 + (hw0 % HWDIM) + 1 - 59;
    const char* gsrc = x8 + (size_t)nl * XP_IMG + (size_t)p0 * PXB;

    #pragma unroll
    for (int c = 0; c < 13; ++c) {                // 13*512*16 >= 104448
        const int off = (c * 512 + tid) * 16;
        if (off < WIN_B) gll16(gsrc + off, xs + off);
    }

    // per-s-fragment setup (4 frags of 32 spatial) while loads fly
    int breg[4], outb[4];
    bool val[4];
    #pragma unroll
    for (int ni = 0; ni < 4; ++ni) {
        int hw = hw0 + sgw * 128 + ni * 32 + lane31;
        val[ni] = (hw < HW2);
        if (!val[ni]) hw = HW2 - 1;
        const int p = (hw / HWDIM + 1) * 58 + (hw % HWDIM) + 1;
        breg[ni] = (p - p0) * PXB + hi * 16 - 16048;   // >= 0; ds offsets positive
        outb[ni] = nl * OUT_NSTR + hw;
    }

    // wave reads co = cow*64 .. +63  (cb2 = cow*2, cow*2+1)
    const char* wb0 = wp + (cow * 2) * WP_CB2STR + l * 16;
    const char* wb1 = wb0 + WP_CB2STR;

    // tap shift (bytes) + 16048 so every LDS literal offset is >= 0
    const int xoffp[9] = {
        16048 - 59 * PXB, 16048 - 58 * PXB, 16048 - 57 * PXB,
        16048 - 1 * PXB,  16048,            16048 + 1 * PXB,
        16048 + 57 * PXB, 16048 + 58 * PXB, 16048 + 59 * PXB
    };

    __syncthreads();                              // stage complete; no more barriers

    v16i acc[2][4] = {};
    v4i wa[4][2];                                 // depth-3 W prefetch ring
    v4i xb[2][4];                                 // depth-1 X prefetch ring

    wa[0][0] = *(const v4i*)(wb0);
    wa[0][1] = *(const v4i*)(wb1);
    wa[1][0] = *(const v4i*)(wb0 + 1024);
    wa[1][1] = *(const v4i*)(wb1 + 1024);
    wa[2][0] = *(const v4i*)(wb0 + 2048);
    wa[2][1] = *(const v4i*)(wb1 + 2048);
    #pragma unroll
    for (int ni = 0; ni < 4; ++ni)
        xb[0][ni] = *(const v4i*)(xs + breg[ni] + xoffp[0]);

    #pragma unroll
    for (int j = 0; j < 72; ++j) {                // j = tap*8 + kb; all idx static
        const int jc = j & 3;
        const int pc = j & 1;
        if (j + 3 < 72) {
            const int jn = (j + 3) & 3;
            wa[jn][0] = *(const v4i*)(wb0 + (j + 3) * 1024);
            wa[jn][1] = *(const v4i*)(wb1 + (j + 3) * 1024);
        }
        if (j + 1 < 72) {
            const int t1 = (j + 1) >> 3, kb1 = (j + 1) & 7;
            const int xo = xoffp[t1] + kb1 * 32;
            #pragma unroll
            for (int ni = 0; ni < 4; ++ni)
                xb[pc ^ 1][ni] = *(const v4i*)(xs + breg[ni] + xo);
        }
        __builtin_amdgcn_s_setprio(1);
        #pragma unroll
        for (int mi = 0; mi < 2; ++mi) {
            #pragma unroll
            for (int ni = 0; ni < 4; ++ni) {
                acc[mi][ni] = __builtin_amdgcn_mfma_i32_32x32x32_i8(
                    wa[jc][mi], xb[pc][ni], acc[mi][ni], 0, 0, 0);
            }
        }
        __builtin_amdgcn_s_setprio(0);
    }

    // C/D: col = lane&31 (spatial), row = (r&3)+8*(r>>2)+4*hi (co)
    // non-temporal stores: keep the 103 MB output stream from evicting W/X in L2
    #pragma unroll
    for (int mi = 0; mi < 2; ++mi) {
        #pragma unroll
        for (int ni = 0; ni < 4; ++ni) {
            if (!val[ni]) continue;
            const v16i c = acc[mi][ni];
            int* ob = out + outb[ni] + (cow * 64 + mi * 32 + 4 * hi) * HW2;
            #pragma unroll
            for (int rr = 0; rr < 16; ++rr) {
                __builtin_nontemporal_store(c[rr], ob + ((rr & 3) + 8 * (rr >> 2)) * HW2);
            }
        }
    }
}

// ---------- fallback: direct conv (correct, slow) ----------
__global__ void dc_naive(const int* __restrict__ x, const int* __restrict__ wt,
                         int* __restrict__ out) {
    const int idx = blockIdx.x * 256 + threadIdx.x;
    if (idx >= OUT_TOT) return;
    const int w = idx % HWDIM;
    const int h = (idx / HWDIM) % HWDIM;
    const int co = (idx / HW2) & 255;
    const int n = idx / OUT_NSTR;
    const int* xn = x + n * OUT_NSTR;
    const int* wo = wt + co * (C_IN * 9);
    int acc = 0;
    for (int ci = 0; ci < C_IN; ++ci) {
        const int* xc = xn + ci * HW2;
        const int* wc = wo + ci * 9;
        #pragma unroll
        for (int kh = 0; kh < 3; ++kh) {
            const int hh = h + kh - 1;
            if ((unsigned)hh >= HWDIM) continue;
            #pragma unroll
            for (int kw = 0; kw < 3; ++kw) {
                const int ww = w + kw - 1;
                if ((unsigned)ww >= HWDIM) continue;
                acc += xc[hh * HWDIM + ww] * wc[kh * 3 + kw];
            }
        }
    }
    out[idx] = acc;
}

extern "C" void kernel_launch(void* const* d_in, const int* in_sizes, int n_in,
                              void* d_out, int out_size, void* d_ws, size_t ws_size,
                              hipStream_t stream) {
    const int* x  = (const int*)d_in[0];
    const int* wt = (const int*)d_in[1];
    int* out = (int*)d_out;

    int chunk = 0;
    const int cand[4] = {32, 16, 8, 4};
    for (int i = 0; i < 4; ++i) {
        if ((size_t)cand[i] * XP_IMG + XP_SLACK + WP_BYTES <= ws_size) { chunk = cand[i]; break; }
    }

    if (chunk > 0) {
        char* x8 = (char*)d_ws;
        const size_t x8_bytes = (size_t)chunk * XP_IMG + XP_SLACK;
        unsigned int* wp = (unsigned int*)(x8 + x8_bytes);
        hipLaunchKernelGGL(dc_halo, dim3(chunk), dim3(256), 0, stream, (unsigned int*)x8);
        hipLaunchKernelGGL(dc_pack_w, dim3(576), dim3(256), 0, stream, wt, wp);
        for (int n0 = 0; n0 < N_IMG; n0 += chunk) {
            hipLaunchKernelGGL(dc_x_to_nhwc, dim3(chunk * HWDIM), dim3(256), 0, stream,
                               x, (unsigned int*)x8, n0);
            const int nwg = chunk * TILES_PER_IMG;
            hipLaunchKernelGGL(dc_mfma, dim3(nwg), dim3(512), WIN_B, stream,
                               (const char*)x8, (const char*)wp,
                               out + (size_t)n0 * OUT_NSTR, nwg);
        }
        return;
    }

    hipLaunchKernelGGL(dc_naive, dim3((OUT_TOT + 255) / 256), dim3(256), 0, stream,
                       x, wt, out);
}